// Round 10
// baseline (65.189 us; speedup 1.0000x reference)
//
#include <hip/hip_runtime.h>
#include <hip/hip_fp16.h>
#include <math.h>

// Siddon forward projection, 128^3 grid over [-1,1]^3, voxel = 1/64.
// fp16 image staged in workspace (4 MB -> L2-resident per XCD).
// K=16 lanes per LOR (alpha chunks); incremental traversal with PACKED
// byte-offset voxel index. The packed index is initialized ARITHMETICALLY
// (ix*2^15 + iy*2^8 + iz*2) so entry-side -1 excursions stay exact linear
// bookkeeping (their segments carry ~1e-7 diff; the first axis advance
// restores a valid index). Past-end/cushion steps get dif=0 via fmaxf, so
// no per-step bounds check is needed; the masked load is always in-range.

static constexpr float VOX = 0.015625f;   // 2/128, exact power of two
static constexpr float INV_VOX = 64.0f;
static constexpr int   K = 16;
static constexpr int   LOGK = 4;
static constexpr int   NVOX = 128 * 128 * 128;
static constexpr int   IDX_MASK = 0x3FFFFE;   // even byte offset, < 4 MB

struct TState {
  float alx, aly, alz;   // next-crossing alpha per axis
  float dax, day, daz;   // alpha increment per crossing
  float acur, aend;
  int   idx;             // packed byte offset: ix*2^15 + iy*2^8 + iz*2
  int   dix, diy, diz;   // packed per-crossing deltas (signed)
};

__device__ __forceinline__ void step4(const __half* __restrict__ image,
                                      TState& S, float dif4[4], float v4[4]) {
#pragma unroll
  for (int j = 0; j < 4; ++j) {
    float anext = fminf(fminf(S.alx, S.aly), S.alz);
    float astop = fminf(anext, S.aend);
    dif4[j] = fmaxf(astop - S.acur, 0.0f);   // degenerate/padded steps -> 0
    int idxm = S.idx & IDX_MASK;             // always in-range
    v4[j] = __half2float(*(const __half*)((const char*)image + idxm));
    S.acur = astop;
    bool cx = S.alx <= anext;
    bool cy = S.aly <= anext;
    bool cz = S.alz <= anext;
    S.idx += (cx ? S.dix : 0) + (cy ? S.diy : 0) + (cz ? S.diz : 0);
    S.alx += cx ? S.dax : 0.0f;
    S.aly += cy ? S.day : 0.0f;
    S.alz += cz ? S.daz : 0.0f;
  }
}

// First plane index strictly past astart in walk order, its alpha, the alpha
// increment, the voxel containing astart, and crossing count in (astart,aend].
__device__ __forceinline__ void axis_init(float astart, float aend, float p0,
                                          float ds, float inv,
                                          int& st, int& iv, float& al, float& da,
                                          int& cnt) {
  float ts = (fmaf(astart, ds, p0) + 1.0f) * INV_VOX;
  float te = (fmaf(aend,   ds, p0) + 1.0f) * INV_VOX;
  int ip;
  if (ds > 0.0f) {
    ip = (int)floorf(ts) + 1;
    int il = (int)floorf(te); if (il > 128) il = 128;
    cnt = il - ip + 1; st = 1; iv = ip - 1;
  } else {
    ip = (int)ceilf(ts) - 1;
    int il = (int)ceilf(te); if (il < 0) il = 0;
    cnt = ip - il + 1; st = -1; iv = ip;
  }
  if (cnt < 0) cnt = 0;
  al = (fmaf((float)ip, VOX, -1.0f) - p0) * inv;
  da = VOX * fabsf(inv);
}

// --- image fp32 -> fp16 (workspace) -----------------------------------------
__global__ __launch_bounds__(256) void convert_h(
    const float* __restrict__ img, __half* __restrict__ h)
{
  int i = blockIdx.x * blockDim.x + threadIdx.x;
  int stride = gridDim.x * blockDim.x;
  for (; i < NVOX; i += stride) h[i] = __float2half(img[i]);
}

// --- traversal ---------------------------------------------------------------
__global__ __launch_bounds__(256) void siddon_fp(
    const __half* __restrict__ image,
    const float* __restrict__ lors,
    float* __restrict__ out, int n)
{
  int t   = blockIdx.x * blockDim.x + threadIdx.x;
  int ray = t >> LOGK;
  int k   = t & (K - 1);
  if (ray >= n) return;

  const float* L = lors + (long)ray * 6;
  float p0x = L[0], p0y = L[1], p0z = L[2];
  float dx  = L[3] - p0x, dy = L[4] - p0y, dz = L[5] - p0z;

  const float eps = 1e-9f;
  float dsx = (fabsf(dx) < eps) ? eps : dx;
  float dsy = (fabsf(dy) < eps) ? eps : dy;
  float dsz = (fabsf(dz) < eps) ? eps : dz;

  float invx = __builtin_amdgcn_rcpf(dsx);
  float invy = __builtin_amdgcn_rcpf(dsy);
  float invz = __builtin_amdgcn_rcpf(dsz);

  float a0 = (-1.0f - p0x) * invx, a1 = (1.0f - p0x) * invx;
  float axmin = fminf(a0, a1), axmax = fmaxf(a0, a1);
  a0 = (-1.0f - p0y) * invy; a1 = (1.0f - p0y) * invy;
  float aymin = fminf(a0, a1), aymax = fmaxf(a0, a1);
  a0 = (-1.0f - p0z) * invz; a1 = (1.0f - p0z) * invz;
  float azmin = fminf(a0, a1), azmax = fmaxf(a0, a1);

  float amin = fmaxf(fmaxf(axmin, aymin), fmaxf(azmin, 0.0f));
  float amax = fminf(fminf(axmax, aymax), fminf(azmax, 1.0f));

  float acc0 = 0.0f, acc1 = 0.0f;
  if (amax > amin) {
    float s      = (amax - amin) * (1.0f / (float)K);
    float astart = fmaf((float)k, s, amin);
    float aend   = (k == K - 1) ? amax : fmaf((float)(k + 1), s, amin);

    TState S;
    S.acur = astart; S.aend = aend;
    int stx, sty, stz, ivx, ivy, ivz, c0, c1, c2;
    axis_init(astart, aend, p0x, dsx, invx, stx, ivx, S.alx, S.dax, c0);
    axis_init(astart, aend, p0y, dsy, invy, sty, ivy, S.aly, S.day, c1);
    axis_init(astart, aend, p0z, dsz, invz, stz, ivz, S.alz, S.daz, c2);
    // ARITHMETIC packing (not OR): stays exact for transient -1 excursions.
    S.idx = ivx * 32768 + ivy * 256 + ivz * 2;
    S.dix = stx * 32768;  S.diy = sty * 256;  S.diz = stz * 2;

    int ns = c0 + c1 + c2 + 3;          // +1 final partial, +2 cushion
    int nb = (ns + 3) >> 2;             // batches of 4
    if (nb < 2) nb = 2;                 // prologue needs two batches

    float difA[4], difB[4], difC[4];
    float vA[4], vB[4], vC[4];

#define ISSUE(X)   step4(image, S, dif##X, v##X)
#define CONSUME(X)                                                  \
    do { acc0 = fmaf(dif##X[0], v##X[0], acc0);                     \
         acc1 = fmaf(dif##X[1], v##X[1], acc1);                     \
         acc0 = fmaf(dif##X[2], v##X[2], acc0);                     \
         acc1 = fmaf(dif##X[3], v##X[3], acc1); } while (0)

    ISSUE(A);
    ISSUE(B);
    int produce = nb - 2;
    while (produce >= 3) {
      ISSUE(C); CONSUME(A);
      ISSUE(A); CONSUME(B);
      ISSUE(B); CONSUME(C);
      produce -= 3;
    }
    if (produce == 2) {
      ISSUE(C); CONSUME(A);
      ISSUE(A); CONSUME(B);
      CONSUME(C); CONSUME(A);
    } else if (produce == 1) {
      ISSUE(C); CONSUME(A);
      CONSUME(B); CONSUME(C);
    } else {
      CONSUME(A); CONSUME(B);
    }
#undef ISSUE
#undef CONSUME

    float rlen = sqrtf(dx * dx + dy * dy + dz * dz);
    acc0 = (acc0 + acc1) * rlen;
    acc1 = 0.0f;
  }

  float acc = acc0 + acc1;
  acc += __shfl_xor(acc, 1);
  acc += __shfl_xor(acc, 2);
  acc += __shfl_xor(acc, 4);
  acc += __shfl_xor(acc, 8);
  if (k == 0) out[ray] = acc;
}

extern "C" void kernel_launch(void* const* d_in, const int* in_sizes, int n_in,
                              void* d_out, int out_size, void* d_ws, size_t ws_size,
                              hipStream_t stream) {
  const float* image = (const float*)d_in[0];   // [128,128,128] f32
  const float* lors  = (const float*)d_in[1];   // [N,6] f32
  float* out = (float*)d_out;                   // [N] f32
  int n = out_size;

  __half* h = (__half*)d_ws;                    // 4 MB fp16 image
  hipLaunchKernelGGL(convert_h, dim3(2048), dim3(256), 0, stream, image, h);

  long total = (long)n * K;
  int block = 256;
  int grid = (int)((total + block - 1) / block);
  hipLaunchKernelGGL(siddon_fp, dim3(grid), dim3(block), 0, stream,
                     h, lors, out, n);
}